// Round 1
// baseline (3476.262 us; speedup 1.0000x reference)
//
#include <hip/hip_runtime.h>
#include <hip/hip_bf16.h>
#include <stdint.h>

#define ALPHA_F 0.2f
#define K_STEPS 10

__device__ __forceinline__ float bf2f(unsigned short u) {
  union { unsigned int i; float f; } v; v.i = ((unsigned int)u) << 16; return v.f;
}
__device__ __forceinline__ unsigned short f2bf(float f) {
  unsigned int x = __float_as_uint(f);
  unsigned int r = (x + 0x7fffu + ((x >> 16) & 1u)) >> 16;
  return (unsigned short)r;
}

// ---------------- graph build ----------------

__global__ void k_init_deg(int* __restrict__ deg, int n) {
  int i = blockIdx.x * blockDim.x + threadIdx.x;
  if (i < n) deg[i] = 1;  // self-loop
}

__global__ void k_hist(const int* __restrict__ dst, int* __restrict__ deg, int E) {
  int e = blockIdx.x * blockDim.x + threadIdx.x;
  if (e < E) atomicAdd(&deg[dst[e]], 1);
}

// single-block exclusive scan over n counts -> rowptr[0..n]
__global__ void k_scan(const int* __restrict__ counts, int* __restrict__ rowptr, int n) {
  __shared__ int tmp[1024];
  __shared__ int carry_s;
  const int tid = threadIdx.x;
  if (tid == 0) carry_s = 0;
  __syncthreads();
  for (int base = 0; base < n; base += 1024) {
    int idx = base + tid;
    int v = (idx < n) ? counts[idx] : 0;
    tmp[tid] = v;
    __syncthreads();
    #pragma unroll
    for (int off = 1; off < 1024; off <<= 1) {
      int t = (tid >= off) ? tmp[tid - off] : 0;
      __syncthreads();
      tmp[tid] += t;
      __syncthreads();
    }
    int c = carry_s;
    if (idx < n) rowptr[idx] = c + tmp[tid] - v;  // exclusive
    __syncthreads();
    if (tid == 0) carry_s = c + tmp[1023];
    __syncthreads();
  }
  if (tid == 0) rowptr[n] = carry_s;
}

__global__ void k_dinv_cursor(const int* __restrict__ deg, const int* __restrict__ rowptr,
                              float* __restrict__ dinv, int* __restrict__ cursor, int n) {
  int i = blockIdx.x * blockDim.x + threadIdx.x;
  if (i < n) {
    dinv[i] = 1.0f / sqrtf((float)deg[i]);  // deg >= 1 always (self-loop)
    cursor[i] = rowptr[i];
  }
}

__global__ void k_scatter(const int* __restrict__ src, const int* __restrict__ dst,
                          int* __restrict__ cursor, int* __restrict__ col, int E, int n) {
  int idx = blockIdx.x * blockDim.x + threadIdx.x;
  if (idx >= E + n) return;
  int s, d;
  if (idx < E) { s = src[idx]; d = dst[idx]; }
  else         { s = d = idx - E; }
  int pos = atomicAdd(&cursor[d], 1);
  col[pos] = s;
}

// ---------------- GEMM (fp32 compute, optional bf16 A-in / bf16 out, bias+relu fused) ----------------
// BM=BN=64, BK=16, 256 threads, 4x4 per thread.

template<bool A_BF16, bool OUT_BF16, bool RELU>
__global__ __launch_bounds__(256)
void k_gemm_bias(const void* __restrict__ Av, const float* __restrict__ B,
                 const float* __restrict__ bias, void* __restrict__ Cv,
                 int M, int N, int K) {
  __shared__ float As[16][68];  // [k][m], stride 68 keeps 16B alignment of As[k][4t]
  __shared__ float Bs[16][68];  // [k][n]
  const int bm = blockIdx.y * 64;
  const int bn = blockIdx.x * 64;
  const int tid = threadIdx.x;
  const int tx = tid & 15;        // n-dir thread coord
  const int ty = tid >> 4;        // m-dir thread coord
  const int arow = tid >> 2;      // 0..63
  const int acolk = (tid & 3) << 2;   // 0,4,8,12
  const int brow = tid >> 4;      // 0..15
  const int bcol = (tid & 15) << 2;   // 0..60
  const bool arow_ok = (bm + arow) < M;

  float acc[4][4];
  #pragma unroll
  for (int i = 0; i < 4; ++i)
    #pragma unroll
    for (int j = 0; j < 4; ++j) acc[i][j] = 0.f;

  for (int k0 = 0; k0 < K; k0 += 16) {
    float av0, av1, av2, av3;
    if (arow_ok) {
      if constexpr (A_BF16) {
        const ushort4 u = *reinterpret_cast<const ushort4*>(
            (const unsigned short*)Av + (size_t)(bm + arow) * K + (k0 + acolk));
        av0 = bf2f(u.x); av1 = bf2f(u.y); av2 = bf2f(u.z); av3 = bf2f(u.w);
      } else {
        const float4 f = *reinterpret_cast<const float4*>(
            (const float*)Av + (size_t)(bm + arow) * K + (k0 + acolk));
        av0 = f.x; av1 = f.y; av2 = f.z; av3 = f.w;
      }
    } else { av0 = av1 = av2 = av3 = 0.f; }
    const float4 bv = *reinterpret_cast<const float4*>(B + (size_t)(k0 + brow) * N + (bn + bcol));
    __syncthreads();
    As[acolk + 0][arow] = av0; As[acolk + 1][arow] = av1;
    As[acolk + 2][arow] = av2; As[acolk + 3][arow] = av3;
    Bs[brow][bcol + 0] = bv.x; Bs[brow][bcol + 1] = bv.y;
    Bs[brow][bcol + 2] = bv.z; Bs[brow][bcol + 3] = bv.w;
    __syncthreads();
    #pragma unroll
    for (int kk = 0; kk < 16; ++kk) {
      const float a0 = As[kk][ty * 4 + 0], a1 = As[kk][ty * 4 + 1];
      const float a2 = As[kk][ty * 4 + 2], a3 = As[kk][ty * 4 + 3];
      const float b0 = Bs[kk][tx * 4 + 0], b1 = Bs[kk][tx * 4 + 1];
      const float b2 = Bs[kk][tx * 4 + 2], b3 = Bs[kk][tx * 4 + 3];
      acc[0][0] += a0 * b0; acc[0][1] += a0 * b1; acc[0][2] += a0 * b2; acc[0][3] += a0 * b3;
      acc[1][0] += a1 * b0; acc[1][1] += a1 * b1; acc[1][2] += a1 * b2; acc[1][3] += a1 * b3;
      acc[2][0] += a2 * b0; acc[2][1] += a2 * b1; acc[2][2] += a2 * b2; acc[2][3] += a2 * b3;
      acc[3][0] += a3 * b0; acc[3][1] += a3 * b1; acc[3][2] += a3 * b2; acc[3][3] += a3 * b3;
    }
  }

  #pragma unroll
  for (int ii = 0; ii < 4; ++ii) {
    const int r = bm + ty * 4 + ii;
    if (r >= M) continue;
    #pragma unroll
    for (int jj = 0; jj < 4; ++jj) {
      const int c = bn + tx * 4 + jj;
      float v = acc[ii][jj] + bias[c];
      if constexpr (RELU) v = fmaxf(v, 0.f);
      if constexpr (OUT_BF16) ((unsigned short*)Cv)[(size_t)r * N + c] = f2bf(v);
      else                    ((float*)Cv)[(size_t)r * N + c] = v;
    }
  }
}

// ---------------- APPNP propagation step ----------------
// 1 wave per node, lane covers 4 dims (float4) -> 256 dims. 4 nodes / block.

__global__ __launch_bounds__(256)
void k_appnp(const float* __restrict__ hprev, const float* __restrict__ h0,
             float* __restrict__ hout, const int* __restrict__ rowptr,
             const int* __restrict__ col, const float* __restrict__ dinv, int n) {
  const int lane = threadIdx.x & 63;
  const int wave = threadIdx.x >> 6;
  const int i = blockIdx.x * 4 + wave;
  if (i >= n) return;
  const int beg = rowptr[i];
  const int end = rowptr[i + 1];
  const int d = lane << 2;
  float4 acc = make_float4(0.f, 0.f, 0.f, 0.f);
  for (int e = beg; e < end; ++e) {
    const int j = col[e];
    const float w = dinv[j];
    const float4 hv = *reinterpret_cast<const float4*>(hprev + (size_t)j * 256 + d);
    acc.x += w * hv.x; acc.y += w * hv.y; acc.z += w * hv.z; acc.w += w * hv.w;
  }
  const float s = (1.0f - ALPHA_F) * dinv[i];
  const float4 h0v = *reinterpret_cast<const float4*>(h0 + (size_t)i * 256 + d);
  float4 o;
  o.x = s * acc.x + ALPHA_F * h0v.x;
  o.y = s * acc.y + ALPHA_F * h0v.y;
  o.z = s * acc.z + ALPHA_F * h0v.z;
  o.w = s * acc.w + ALPHA_F * h0v.w;
  *reinterpret_cast<float4*>(hout + (size_t)i * 256 + d) = o;
}

// ---------------- launch ----------------

extern "C" void kernel_launch(void* const* d_in, const int* in_sizes, int n_in,
                              void* d_out, int out_size, void* d_ws, size_t ws_size,
                              hipStream_t stream) {
  const float* x  = (const float*)d_in[0];
  const int*   ei = (const int*)d_in[1];
  const float* W1 = (const float*)d_in[2];
  const float* b1 = (const float*)d_in[3];
  const float* W2 = (const float*)d_in[4];
  const float* b2 = (const float*)d_in[5];
  const float* W3 = (const float*)d_in[6];
  const float* b3 = (const float*)d_in[7];

  const int HID  = in_sizes[3];            // 512
  const int IN   = in_sizes[2] / HID;      // 512
  const int OUTD = in_sizes[7];            // 256
  const int E    = in_sizes[1] / 2;        // 1,600,000
  const int N    = in_sizes[0] / IN;       // 50,000
  const int* src = ei;
  const int* dst = ei + E;

  char* ws = (char*)d_ws;
  size_t off = 0;
  auto alloc = [&](size_t bytes) {
    char* p = ws + off;
    off += (bytes + 255) & ~(size_t)255;
    return p;
  };
  // region A: h1 (bf16 N*HID) later aliased as h0 (fp32 N*OUTD) -- same byte size
  unsigned short* h1 = (unsigned short*)alloc((size_t)N * HID * 2);
  float* h0 = (float*)h1;
  // region B: h2 (bf16 N*HID) later aliased as ping (fp32 N*OUTD)
  unsigned short* h2 = (unsigned short*)alloc((size_t)N * HID * 2);
  float* ping = (float*)h2;
  int*   deg    = (int*)alloc((size_t)N * 4);
  int*   rowptr = (int*)alloc((size_t)(N + 1) * 4);
  int*   cursor = (int*)alloc((size_t)N * 4);
  float* dinv   = (float*)alloc((size_t)N * 4);
  int*   col    = (int*)alloc((size_t)(E + N) * 4);
  (void)ws_size; (void)n_in;

  // graph build
  k_init_deg<<<(N + 255) / 256, 256, 0, stream>>>(deg, N);
  k_hist<<<(E + 255) / 256, 256, 0, stream>>>(dst, deg, E);
  k_scan<<<1, 1024, 0, stream>>>(deg, rowptr, N);
  k_dinv_cursor<<<(N + 255) / 256, 256, 0, stream>>>(deg, rowptr, dinv, cursor, N);
  k_scatter<<<(E + N + 255) / 256, 256, 0, stream>>>(src, dst, cursor, col, E, N);

  // MLP encoder
  dim3 blk(256);
  dim3 g1(HID / 64, (N + 63) / 64);
  k_gemm_bias<false, true, true><<<g1, blk, 0, stream>>>(x, W1, b1, h1, N, HID, IN);
  k_gemm_bias<true, true, true><<<g1, blk, 0, stream>>>(h1, W2, b2, h2, N, HID, HID);
  dim3 g3(OUTD / 64, (N + 63) / 64);
  k_gemm_bias<true, false, false><<<g3, blk, 0, stream>>>(h2, W3, b3, h0, N, OUTD, HID);

  // APPNP propagation: ping-pong between ping (region B) and d_out; final step -> d_out
  float* out = (float*)d_out;
  const float* cur = h0;
  const int nblk = (N + 3) / 4;
  for (int step = 0; step < K_STEPS; ++step) {
    float* dbuf = (step % 2 == 0) ? ping : out;
    k_appnp<<<nblk, 256, 0, stream>>>(cur, h0, dbuf, rowptr, col, dinv, N);
    cur = dbuf;
  }
}

// Round 2
// 2794.818 us; speedup vs baseline: 1.2438x; 1.2438x over previous
//
#include <hip/hip_runtime.h>
#include <hip/hip_bf16.h>
#include <stdint.h>

#define ALPHA_F 0.2f
#define K_STEPS 10

typedef __attribute__((ext_vector_type(8))) short short8;
typedef __attribute__((ext_vector_type(4))) float f32x4;

__device__ __forceinline__ float bf2f(unsigned short u) {
  union { unsigned int i; float f; } v; v.i = ((unsigned int)u) << 16; return v.f;
}
__device__ __forceinline__ unsigned short f2bf(float f) {
  unsigned int x = __float_as_uint(f);
  unsigned int r = (x + 0x7fffu + ((x >> 16) & 1u)) >> 16;
  return (unsigned short)r;
}

__device__ __forceinline__ void glds16(const void* g, void* l) {
  __builtin_amdgcn_global_load_lds(
      (const __attribute__((address_space(1))) void*)g,
      (__attribute__((address_space(3))) void*)l, 16, 0, 0);
}

// ---------------- graph build ----------------

__global__ void k_init_deg(int* __restrict__ deg, int n) {
  int i = blockIdx.x * blockDim.x + threadIdx.x;
  if (i < n) deg[i] = 1;  // self-loop
}

__global__ void k_hist(const int* __restrict__ dst, int* __restrict__ deg, int E) {
  int e = blockIdx.x * blockDim.x + threadIdx.x;
  if (e < E) atomicAdd(&deg[dst[e]], 1);
}

// single-block exclusive scan over n counts -> rowptr[0..n]
__global__ void k_scan(const int* __restrict__ counts, int* __restrict__ rowptr, int n) {
  __shared__ int tmp[1024];
  __shared__ int carry_s;
  const int tid = threadIdx.x;
  if (tid == 0) carry_s = 0;
  __syncthreads();
  for (int base = 0; base < n; base += 1024) {
    int idx = base + tid;
    int v = (idx < n) ? counts[idx] : 0;
    tmp[tid] = v;
    __syncthreads();
    #pragma unroll
    for (int off = 1; off < 1024; off <<= 1) {
      int t = (tid >= off) ? tmp[tid - off] : 0;
      __syncthreads();
      tmp[tid] += t;
      __syncthreads();
    }
    int c = carry_s;
    if (idx < n) rowptr[idx] = c + tmp[tid] - v;  // exclusive
    __syncthreads();
    if (tid == 0) carry_s = c + tmp[1023];
    __syncthreads();
  }
  if (tid == 0) rowptr[n] = carry_s;
}

__global__ void k_dinv_cursor(const int* __restrict__ deg, const int* __restrict__ rowptr,
                              float* __restrict__ dinv, int* __restrict__ cursor, int n) {
  int i = blockIdx.x * blockDim.x + threadIdx.x;
  if (i < n) {
    dinv[i] = 1.0f / sqrtf((float)deg[i]);  // deg >= 1 always (self-loop)
    cursor[i] = rowptr[i];
  }
}

__global__ void k_scatter(const int* __restrict__ src, const int* __restrict__ dst,
                          int* __restrict__ cursor, int* __restrict__ col,
                          float* __restrict__ wgt, const float* __restrict__ dinv,
                          int E, int n) {
  int idx = blockIdx.x * blockDim.x + threadIdx.x;
  if (idx >= E + n) return;
  int s, d;
  if (idx < E) { s = src[idx]; d = dst[idx]; }
  else         { s = d = idx - E; }
  int pos = atomicAdd(&cursor[d], 1);
  col[pos] = s;
  wgt[pos] = dinv[s];
}

// ---------------- converts ----------------

// fp32 -> bf16, 8 elems/thread, zero-fill pad rows
__global__ void k_f2b8(const float* __restrict__ src, unsigned short* __restrict__ dst,
                       int validRows, int cols, long total8) {
  long idx = (long)blockIdx.x * blockDim.x + threadIdx.x;
  if (idx >= total8) return;
  size_t base = (size_t)idx * 8;
  int row = (int)(base / (size_t)cols);
  uint4 o;
  if (row < validRows) {
    const float4 f0 = *reinterpret_cast<const float4*>(src + base);
    const float4 f1 = *reinterpret_cast<const float4*>(src + base + 4);
    o.x = f2bf(f0.x) | ((unsigned)f2bf(f0.y) << 16);
    o.y = f2bf(f0.z) | ((unsigned)f2bf(f0.w) << 16);
    o.z = f2bf(f1.x) | ((unsigned)f2bf(f1.y) << 16);
    o.w = f2bf(f1.z) | ((unsigned)f2bf(f1.w) << 16);
  } else {
    o = make_uint4(0, 0, 0, 0);
  }
  *reinterpret_cast<uint4*>(dst + base) = o;
}

// W [K][Nw] fp32 -> Wt [Nw][K] bf16
__global__ void k_wtrans(const float* __restrict__ W, unsigned short* __restrict__ Wt,
                         int K, int Nw) {
  int idx = blockIdx.x * blockDim.x + threadIdx.x;
  if (idx >= K * Nw) return;
  int nn = idx / K, kk = idx - nn * K;
  Wt[(size_t)nn * K + kk] = f2bf(W[(size_t)kk * Nw + nn]);
}

// ---------------- MFMA GEMM ----------------
// C[M][Nn] = A[M][K]_bf16 @ Bt[Nn][K]_bf16^T + bias, 128x128 tile, BK=32,
// 256 threads = 4 waves (2x2), each wave 64x64 = 4x4 fragments of 16x16x32.
// M must be padded to 128 (buffers padded; stores unguarded).

template<bool OUT_BF16, bool RELU>
__global__ __launch_bounds__(256)
void k_gemm_mfma(const unsigned short* __restrict__ A,
                 const unsigned short* __restrict__ Bt,
                 const float* __restrict__ bias,
                 void* __restrict__ C, int Nn, int K) {
  __shared__ unsigned short As[128 * 32];
  __shared__ unsigned short Bs[128 * 32];
  const int tid = threadIdx.x;
  const int lane = tid & 63;
  const int wid = tid >> 6;
  const int wr = wid >> 1, wc = wid & 1;
  const int bm = blockIdx.y * 128;
  const int bn = blockIdx.x * 128;

  f32x4 acc[4][4];
  #pragma unroll
  for (int i = 0; i < 4; ++i)
    #pragma unroll
    for (int j = 0; j < 4; ++j) acc[i][j] = (f32x4)0.f;

  // staging: thread t loads 16B (8 bf16): row = t>>2, k-group = (t&3)*8
  const int srow = tid >> 2;
  const int skg = (tid & 3) << 3;
  const unsigned short* Ag = A + (size_t)(bm + srow) * K + skg;
  const unsigned short* Bg = Bt + (size_t)(bn + srow) * K + skg;
  unsigned short* lA = As + (wid << 9);   // wave-uniform base; HW adds lane*16B
  unsigned short* lB = Bs + (wid << 9);

  const int frow = lane & 15;
  const int fk = (lane >> 4) << 3;

  for (int k0 = 0; k0 < K; k0 += 32) {
    __syncthreads();  // previous tile's reads complete before overwrite
    glds16(Ag + k0, lA);
    glds16(Ag + (size_t)64 * K + k0, lA + 2048);
    glds16(Bg + k0, lB);
    glds16(Bg + (size_t)64 * K + k0, lB + 2048);
    __syncthreads();  // barrier drains vmcnt -> tile visible

    short8 af[4], bq[4];
    #pragma unroll
    for (int mi = 0; mi < 4; ++mi)
      af[mi] = *reinterpret_cast<const short8*>(&As[(wr * 64 + mi * 16 + frow) * 32 + fk]);
    #pragma unroll
    for (int ni = 0; ni < 4; ++ni)
      bq[ni] = *reinterpret_cast<const short8*>(&Bs[(wc * 64 + ni * 16 + frow) * 32 + fk]);
    #pragma unroll
    for (int mi = 0; mi < 4; ++mi)
      #pragma unroll
      for (int ni = 0; ni < 4; ++ni)
        acc[mi][ni] = __builtin_amdgcn_mfma_f32_16x16x32_bf16(af[mi], bq[ni], acc[mi][ni], 0, 0, 0);
  }

  // epilogue: C/D layout col=lane&15, row=(lane>>4)*4+reg
  const int r0 = bm + wr * 64;
  const int c0 = bn + wc * 64;
  #pragma unroll
  for (int ni = 0; ni < 4; ++ni) {
    const int c = c0 + ni * 16 + (lane & 15);
    const float bv = bias[c];
    #pragma unroll
    for (int mi = 0; mi < 4; ++mi) {
      #pragma unroll
      for (int r = 0; r < 4; ++r) {
        const int row = r0 + mi * 16 + ((lane >> 4) << 2) + r;
        float v = acc[mi][ni][r] + bv;
        if constexpr (RELU) v = fmaxf(v, 0.f);
        if constexpr (OUT_BF16)
          ((unsigned short*)C)[(size_t)row * Nn + c] = f2bf(v);
        else
          ((float*)C)[(size_t)row * Nn + c] = v;
      }
    }
  }
}

// ---------------- APPNP propagation step ----------------
// 1 wave per node, lane covers 4 dims (float4) -> 256 dims. 4 nodes / block.

__global__ __launch_bounds__(256)
void k_appnp(const float* __restrict__ hprev, const float* __restrict__ h0,
             float* __restrict__ hout, const int* __restrict__ rowptr,
             const int* __restrict__ col, const float* __restrict__ wgt,
             const float* __restrict__ dinv, int n) {
  const int lane = threadIdx.x & 63;
  const int i = blockIdx.x * 4 + (threadIdx.x >> 6);
  if (i >= n) return;
  const int beg = rowptr[i];
  const int end = rowptr[i + 1];
  const int d = lane << 2;
  float ax = 0.f, ay = 0.f, az = 0.f, aw = 0.f;
  int e = beg;
  for (; e + 4 <= end; e += 4) {
    const int j0 = col[e], j1 = col[e + 1], j2 = col[e + 2], j3 = col[e + 3];
    const float w0 = wgt[e], w1 = wgt[e + 1], w2 = wgt[e + 2], w3 = wgt[e + 3];
    const float4 v0 = *reinterpret_cast<const float4*>(hprev + (size_t)j0 * 256 + d);
    const float4 v1 = *reinterpret_cast<const float4*>(hprev + (size_t)j1 * 256 + d);
    const float4 v2 = *reinterpret_cast<const float4*>(hprev + (size_t)j2 * 256 + d);
    const float4 v3 = *reinterpret_cast<const float4*>(hprev + (size_t)j3 * 256 + d);
    ax += w0 * v0.x + w1 * v1.x + w2 * v2.x + w3 * v3.x;
    ay += w0 * v0.y + w1 * v1.y + w2 * v2.y + w3 * v3.y;
    az += w0 * v0.z + w1 * v1.z + w2 * v2.z + w3 * v3.z;
    aw += w0 * v0.w + w1 * v1.w + w2 * v2.w + w3 * v3.w;
  }
  for (; e < end; ++e) {
    const int j = col[e];
    const float w = wgt[e];
    const float4 v = *reinterpret_cast<const float4*>(hprev + (size_t)j * 256 + d);
    ax += w * v.x; ay += w * v.y; az += w * v.z; aw += w * v.w;
  }
  const float s = (1.0f - ALPHA_F) * dinv[i];
  const float4 h0v = *reinterpret_cast<const float4*>(h0 + (size_t)i * 256 + d);
  float4 o;
  o.x = s * ax + ALPHA_F * h0v.x;
  o.y = s * ay + ALPHA_F * h0v.y;
  o.z = s * az + ALPHA_F * h0v.z;
  o.w = s * aw + ALPHA_F * h0v.w;
  *reinterpret_cast<float4*>(hout + (size_t)i * 256 + d) = o;
}

// ---------------- launch ----------------

extern "C" void kernel_launch(void* const* d_in, const int* in_sizes, int n_in,
                              void* d_out, int out_size, void* d_ws, size_t ws_size,
                              hipStream_t stream) {
  const float* x  = (const float*)d_in[0];
  const int*   ei = (const int*)d_in[1];
  const float* W1 = (const float*)d_in[2];
  const float* b1 = (const float*)d_in[3];
  const float* W2 = (const float*)d_in[4];
  const float* b2 = (const float*)d_in[5];
  const float* W3 = (const float*)d_in[6];
  const float* b3 = (const float*)d_in[7];

  const int HID  = in_sizes[3];            // 512
  const int IN   = in_sizes[2] / HID;      // 512
  const int OUTD = in_sizes[7];            // 256
  const int E    = in_sizes[1] / 2;        // 1,600,000
  const int N    = in_sizes[0] / IN;       // 50,000
  const int Mpad = (N + 127) & ~127;       // 50,048
  const int* src = ei;
  const int* dst = ei + E;

  char* ws = (char*)d_ws;
  size_t off = 0;
  auto alloc = [&](size_t bytes) {
    char* p = ws + off;
    off += (bytes + 255) & ~(size_t)255;
    return p;
  };
  // R1: xb [Mpad][IN] bf16 -> (after GEMM1 consumes it) h2 [Mpad][HID] bf16
  char* R1 = alloc((size_t)Mpad * ((IN > HID) ? IN : HID) * 2);
  // R2: h1 [Mpad][HID] bf16 -> (after GEMM2) ping [Mpad][OUTD] fp32
  char* R2 = alloc((size_t)Mpad * HID * 2);
  // R4: h0 [Mpad][OUTD] fp32
  char* R4 = alloc((size_t)Mpad * OUTD * 4);
  int*   deg    = (int*)alloc((size_t)N * 4);
  int*   rowptr = (int*)alloc((size_t)(N + 1) * 4);
  int*   cursor = (int*)alloc((size_t)N * 4);
  float* dinv   = (float*)alloc((size_t)N * 4);
  int*   col    = (int*)alloc((size_t)(E + N) * 4);
  float* wgt    = (float*)alloc((size_t)(E + N) * 4);
  unsigned short* W1t = (unsigned short*)alloc((size_t)IN * HID * 2);
  unsigned short* W2t = (unsigned short*)alloc((size_t)HID * HID * 2);
  unsigned short* W3t = (unsigned short*)alloc((size_t)HID * OUTD * 2);
  (void)ws_size; (void)n_in; (void)out_size;

  unsigned short* xb = (unsigned short*)R1;
  unsigned short* h1 = (unsigned short*)R2;
  unsigned short* h2 = (unsigned short*)R1;
  float* h0   = (float*)R4;
  float* ping = (float*)R2;

  // graph build
  k_init_deg<<<(N + 255) / 256, 256, 0, stream>>>(deg, N);
  k_hist<<<(E + 255) / 256, 256, 0, stream>>>(dst, deg, E);
  k_scan<<<1, 1024, 0, stream>>>(deg, rowptr, N);
  k_dinv_cursor<<<(N + 255) / 256, 256, 0, stream>>>(deg, rowptr, dinv, cursor, N);
  k_scatter<<<(E + N + 255) / 256, 256, 0, stream>>>(src, dst, cursor, col, wgt, dinv, E, N);

  // converts
  {
    long total8 = (long)Mpad * IN / 8;
    k_f2b8<<<(int)((total8 + 255) / 256), 256, 0, stream>>>(x, xb, N, IN, total8);
    k_wtrans<<<(IN * HID + 255) / 256, 256, 0, stream>>>(W1, W1t, IN, HID);
    k_wtrans<<<(HID * HID + 255) / 256, 256, 0, stream>>>(W2, W2t, HID, HID);
    k_wtrans<<<(HID * OUTD + 255) / 256, 256, 0, stream>>>(W3, W3t, HID, OUTD);
  }

  // MLP encoder (MFMA)
  {
    dim3 blk(256);
    dim3 g1(HID / 128, Mpad / 128);
    k_gemm_mfma<true, true><<<g1, blk, 0, stream>>>(xb, W1t, b1, h1, HID, IN);
    k_gemm_mfma<true, true><<<g1, blk, 0, stream>>>(h1, W2t, b2, h2, HID, HID);
    dim3 g3(OUTD / 128, Mpad / 128);
    k_gemm_mfma<false, false><<<g3, blk, 0, stream>>>(h2, W3t, b3, h0, OUTD, HID);
  }

  // APPNP propagation: ping-pong; final (10th) step lands in d_out
  float* out = (float*)d_out;
  const float* cur = h0;
  const int nblk = (N + 3) / 4;
  for (int step = 0; step < K_STEPS; ++step) {
    float* dbuf = (step % 2 == 0) ? ping : out;
    k_appnp<<<nblk, 256, 0, stream>>>(cur, h0, dbuf, rowptr, col, wgt, dinv, N);
    cur = dbuf;
  }
}